// Round 7
// baseline (317.402 us; speedup 1.0000x reference)
//
#include <hip/hip_runtime.h>

#define LOG2E 1.4426950408889634f

// ---------- bf16 helpers (raw ushort representation) ----------
__device__ __forceinline__ float b2f(unsigned short u) {
    unsigned int v = ((unsigned int)u) << 16;
    return __builtin_bit_cast(float, v);
}
__device__ __forceinline__ unsigned short f2b(float f) {
    unsigned int u = __builtin_bit_cast(unsigned int, f);
    u += 0x7fffu + ((u >> 16) & 1u);   // round-to-nearest-even
    return (unsigned short)(u >> 16);
}
__device__ __forceinline__ float fexp(float x) {           // e^x
    return __builtin_amdgcn_exp2f(x * LOG2E);
}
__device__ __forceinline__ float silu_f(float x) {
    return x * __builtin_amdgcn_rcpf(1.0f + fexp(-x));
}

// async global->LDS 16B per lane; lptr must be wave-uniform (dest = base + lane*16)
typedef const __attribute__((address_space(1))) unsigned int* gas_t;
typedef __attribute__((address_space(3))) unsigned int* las_t;
__device__ __forceinline__ void gl2lds16(const unsigned short* g, unsigned short* l) {
    __builtin_amdgcn_global_load_lds((gas_t)(const void*)g, (las_t)(void*)l, 16, 0, 0);
}

// ---------- fused fp32 -> bf16 cast for all 4 arrays, one launch ----------
__global__ __launch_bounds__(256) void cvt_all_k(const float* __restrict__ x,
                                                 const float* __restrict__ W_in,
                                                 const float* __restrict__ W_out,
                                                 const float* __restrict__ W_x,
                                                 unsigned short* __restrict__ xb,
                                                 unsigned short* __restrict__ wib,
                                                 unsigned short* __restrict__ wob,
                                                 unsigned short* __restrict__ wxb) {
    int b = blockIdx.x;
    const float* src;
    unsigned short* dst;
    if (b < 4096)       { src = x;     dst = xb;  }
    else if (b < 8192)  { src = W_in;  dst = wib; b -= 4096; }
    else if (b < 10240) { src = W_out; dst = wob; b -= 8192; }
    else                { src = W_x;   dst = wxb; b -= 10240; }
    int i = b * 256 + threadIdx.x;
    float4 v = ((const float4*)src)[i];
    *(ushort4*)(dst + (size_t)i * 4) = make_ushort4(f2b(v.x), f2b(v.y), f2b(v.z), f2b(v.w));
}

// ---------- bf16 MFMA GEMM: C[M,N] = A[M,K] * B[N,K]^T ----------
// 128x128 tile, BK=64, global_load_lds w=16, XOR-swizzled (conflicts=0, verified R3).
typedef __bf16 bf16x8 __attribute__((ext_vector_type(8)));
typedef float  fx4    __attribute__((ext_vector_type(4)));
typedef int    ix4    __attribute__((ext_vector_type(4)));
union FragU { ix4 i; bf16x8 b; };

template <bool OUT_BF16>
__global__ __launch_bounds__(256) void gemm_bt(const unsigned short* __restrict__ A,
                                               const unsigned short* __restrict__ B,
                                               void* __restrict__ C, int N, int K) {
    __shared__ __align__(16) unsigned short sA[128 * 64];
    __shared__ __align__(16) unsigned short sB[128 * 64];
    const int tid  = threadIdx.x;
    const int lane = tid & 63, wave = tid >> 6;
    const int bm = blockIdx.y * 128, bn = blockIdx.x * 128;
    const int wm = (wave >> 1) * 64, wn = (wave & 1) * 64;
    const int row16 = lane & 15, quad = lane >> 4;
    const int srow = lane >> 3;
    const int sc16 = (lane & 7) ^ srow;
    const unsigned short* gA = A + (size_t)(bm + wave * 32 + srow) * K + sc16 * 8;
    const unsigned short* gB = B + (size_t)(bn + wave * 32 + srow) * K + sc16 * 8;
    unsigned short* lA = sA + (wave * 4) * 512;   // wave-uniform
    unsigned short* lB = sB + (wave * 4) * 512;
    fx4 acc[4][4] = {};

    for (int kt = 0; kt < K; kt += 64) {
#pragma unroll
        for (int it = 0; it < 4; ++it) {
            gl2lds16(gA + (size_t)it * 8 * K + kt, lA + it * 512);
            gl2lds16(gB + (size_t)it * 8 * K + kt, lB + it * 512);
        }
        __syncthreads();
#pragma unroll
        for (int kk = 0; kk < 64; kk += 32) {
            FragU af[4], bf[4];
#pragma unroll
            for (int t = 0; t < 4; ++t) {
                int ra = wm + t * 16 + row16;
                af[t].i = *(const ix4*)(sA + ra * 64 + ((quad + (kk >> 3)) ^ (ra & 7)) * 8);
            }
#pragma unroll
            for (int t = 0; t < 4; ++t) {
                int rb = wn + t * 16 + row16;
                bf[t].i = *(const ix4*)(sB + rb * 64 + ((quad + (kk >> 3)) ^ (rb & 7)) * 8);
            }
#pragma unroll
            for (int tm = 0; tm < 4; ++tm)
#pragma unroll
                for (int tn = 0; tn < 4; ++tn)
                    acc[tm][tn] = __builtin_amdgcn_mfma_f32_16x16x32_bf16(
                        af[tm].b, bf[tn].b, acc[tm][tn], 0, 0, 0);
        }
        __syncthreads();
    }
#pragma unroll
    for (int tm = 0; tm < 4; ++tm) {
        int row0 = bm + wm + tm * 16 + quad * 4;
#pragma unroll
        for (int tn = 0; tn < 4; ++tn) {
            int col = bn + wn + tn * 16 + row16;
#pragma unroll
            for (int r = 0; r < 4; ++r) {
                float v = acc[tm][tn][r];
                if (OUT_BF16)
                    ((unsigned short*)C)[(size_t)(row0 + r) * N + col] = f2b(v);
                else
                    ((float*)C)[(size_t)(row0 + r) * N + col] = v;
            }
        }
    }
}

// ---------- narrow GEMM for C[M,1024]: 128x64 tile, 512 blocks = 2/CU ----------
__global__ __launch_bounds__(256) void gemm_bt_n64(const unsigned short* __restrict__ A,
                                                   const unsigned short* __restrict__ B,
                                                   float* __restrict__ C, int N, int K) {
    __shared__ __align__(16) unsigned short sA[128 * 64];
    __shared__ __align__(16) unsigned short sB[64 * 64];
    const int tid  = threadIdx.x;
    const int lane = tid & 63, wave = tid >> 6;
    const int bm = blockIdx.y * 128, bn = blockIdx.x * 64;
    const int wm = wave * 32;
    const int row16 = lane & 15, quad = lane >> 4;
    const int srow = lane >> 3;
    const int sc16 = (lane & 7) ^ srow;
    const unsigned short* gA = A + (size_t)(bm + wave * 32 + srow) * K + sc16 * 8;
    const unsigned short* gB = B + (size_t)(bn + wave * 16 + srow) * K + sc16 * 8;
    unsigned short* lA = sA + (wave * 4) * 512;
    unsigned short* lB = sB + (wave * 2) * 512;
    fx4 acc[2][4] = {};

    for (int kt = 0; kt < K; kt += 64) {
#pragma unroll
        for (int it = 0; it < 4; ++it)
            gl2lds16(gA + (size_t)it * 8 * K + kt, lA + it * 512);
#pragma unroll
        for (int it = 0; it < 2; ++it)
            gl2lds16(gB + (size_t)it * 8 * K + kt, lB + it * 512);
        __syncthreads();
#pragma unroll
        for (int kk = 0; kk < 64; kk += 32) {
            FragU af[2], bf[4];
#pragma unroll
            for (int t = 0; t < 2; ++t) {
                int ra = wm + t * 16 + row16;
                af[t].i = *(const ix4*)(sA + ra * 64 + ((quad + (kk >> 3)) ^ (ra & 7)) * 8);
            }
#pragma unroll
            for (int t = 0; t < 4; ++t) {
                int rb = t * 16 + row16;
                bf[t].i = *(const ix4*)(sB + rb * 64 + ((quad + (kk >> 3)) ^ (rb & 7)) * 8);
            }
#pragma unroll
            for (int tm = 0; tm < 2; ++tm)
#pragma unroll
                for (int tn = 0; tn < 4; ++tn)
                    acc[tm][tn] = __builtin_amdgcn_mfma_f32_16x16x32_bf16(
                        af[tm].b, bf[tn].b, acc[tm][tn], 0, 0, 0);
        }
        __syncthreads();
    }
#pragma unroll
    for (int tm = 0; tm < 2; ++tm) {
        int row0 = bm + wm + tm * 16 + quad * 4;
#pragma unroll
        for (int tn = 0; tn < 4; ++tn) {
            int col = bn + tn * 16 + row16;
#pragma unroll
            for (int r = 0; r < 4; ++r)
                C[(size_t)(row0 + r) * N + col] = acc[tm][tn][r];
        }
    }
}

// ---------- fused middle: conv+silu -> LDS xc -> xproj MFMA -> delta/G -> SSM -> y2 ----------
// R7: 4-row tiles, grid 1024 (4 blocks/CU). R6 post-mortem: occupancy was NOT the
// binding constraint (2x occupancy, same time) — per-thread serial load chains were.
// Phase 1 preloads the whole 7-row conv window; phase 3 prefetches all z rows.
// LDS xc layout: row-major 4x2048 bf16, 16B-col XOR swizzle (phys c16 = c16 ^ (j&3)).
__global__ __launch_bounds__(256, 4) void fused_mid_k(const unsigned short* __restrict__ xz,
                                                      const float* __restrict__ cw,
                                                      const unsigned short* __restrict__ wxb,
                                                      const float* __restrict__ Alog,
                                                      const float* __restrict__ Dv,
                                                      unsigned short* __restrict__ y2) {
    __shared__ __align__(16) unsigned short sxc[4 * 2048];    // 16 KB
    __shared__ float sX[4][16][49];                            // 12.5 KB
    __shared__ float sdg[4 * 17];
    const int tid  = threadIdx.x;
    const int lane = tid & 63, wave = tid >> 6;
    const int row16 = lane & 15, quad = lane >> 4;
    const int m0 = blockIdx.x * 4;

    // ---- phase 1: conv(K=4, causal) + silu for 4 rows x 2048 ch ----
    {
        const int s0 = m0 & 2047;
        ushort4 ua[7], ub[7];
#pragma unroll
        for (int t = 0; t < 7; ++t) {
            int mr = (s0 - 3 + t >= 0) ? (m0 - 3 + t) : m0;   // clamped, masked below
            const unsigned short* p = xz + (size_t)mr * 4096 + tid * 8;
            ua[t] = *(const ushort4*)p;
            ub[t] = *(const ushort4*)(p + 4);
        }
        const float4* cw4 = (const float4*)cw;
        float w[8][4];
#pragma unroll
        for (int c = 0; c < 8; ++c) {
            float4 t4 = cw4[tid * 8 + c];
            w[c][0] = t4.x; w[c][1] = t4.y; w[c][2] = t4.z; w[c][3] = t4.w;
        }
        float v[7][8];
#pragma unroll
        for (int t = 0; t < 7; ++t) {
            bool valid = (s0 - 3 + t >= 0);
            v[t][0] = valid ? b2f(ua[t].x) : 0.f;
            v[t][1] = valid ? b2f(ua[t].y) : 0.f;
            v[t][2] = valid ? b2f(ua[t].z) : 0.f;
            v[t][3] = valid ? b2f(ua[t].w) : 0.f;
            v[t][4] = valid ? b2f(ub[t].x) : 0.f;
            v[t][5] = valid ? b2f(ub[t].y) : 0.f;
            v[t][6] = valid ? b2f(ub[t].z) : 0.f;
            v[t][7] = valid ? b2f(ub[t].w) : 0.f;
        }
#pragma unroll
        for (int j = 0; j < 4; ++j) {
            float acc[8];
#pragma unroll
            for (int c = 0; c < 8; ++c) {
                acc[c] = v[j][c] * w[c][0] + v[j + 1][c] * w[c][1]
                       + v[j + 2][c] * w[c][2] + v[j + 3][c] * w[c][3];
            }
            unsigned short* q = sxc + j * 2048 + ((tid ^ (j & 3)) * 8);
            *(ushort4*)q       = make_ushort4(f2b(silu_f(acc[0])), f2b(silu_f(acc[1])),
                                              f2b(silu_f(acc[2])), f2b(silu_f(acc[3])));
            *(ushort4*)(q + 4) = make_ushort4(f2b(silu_f(acc[4])), f2b(silu_f(acc[5])),
                                              f2b(silu_f(acc[6])), f2b(silu_f(acc[7])));
        }
    }
    __syncthreads();

    // ---- phase 2: xproj = xc @ Wx^T (N=33 pad 48); wave = K-quarter; A from LDS ----
    // A rows 4..15 duplicate rows 0..3 (row16&3); their D rows are discarded.
    {
        fx4 acc[3] = {};
        const unsigned short* bp = wxb + (size_t)row16 * 2048 + wave * 512 + quad * 8;
        const int arow = row16 & 3;
        const int cbase = wave * 64 + quad;
#pragma unroll 4
        for (int kk = 0; kk < 512; kk += 32) {
            FragU a, b0, b1, b2;
            int c16 = cbase + (kk >> 3);
            a.i  = *(const ix4*)(sxc + arow * 2048 + ((c16 ^ arow) * 8));
            b0.i = *(const ix4*)(bp + kk);
            b1.i = *(const ix4*)(bp + 16 * 2048 + kk);
            b2.i = *(const ix4*)(bp + 32 * 2048 + kk);
            acc[0] = __builtin_amdgcn_mfma_f32_16x16x32_bf16(a.b, b0.b, acc[0], 0, 0, 0);
            acc[1] = __builtin_amdgcn_mfma_f32_16x16x32_bf16(a.b, b1.b, acc[1], 0, 0, 0);
            acc[2] = __builtin_amdgcn_mfma_f32_16x16x32_bf16(a.b, b2.b, acc[2], 0, 0, 0);
        }
#pragma unroll
        for (int t = 0; t < 3; ++t)
#pragma unroll
            for (int r = 0; r < 4; ++r)
                sX[wave][quad * 4 + r][t * 16 + row16] = acc[t][r];
    }
    __syncthreads();
    for (int idx = tid; idx < 68; idx += 256) {
        int rr = idx / 17, q = idx - rr * 17;
        float o;
        if (q == 0) {
            float v = sX[0][rr][0] + sX[1][rr][0] + sX[2][rr][0] + sX[3][rr][0];
            o = (v > 20.f) ? v : log1pf(fexp(v));          // softplus(delta_raw)
        } else {
            float bs = sX[0][rr][q]      + sX[1][rr][q]      + sX[2][rr][q]      + sX[3][rr][q];
            float cs = sX[0][rr][q + 16] + sX[1][rr][q + 16] + sX[2][rr][q + 16] + sX[3][rr][q + 16];
            o = bs * cs;                                   // G[n] = B[n]*C[n]
        }
        sdg[rr * 17 + q] = o;
    }
    __syncthreads();

    // ---- phase 3: SSM pointwise; 2 passes x 4 ch/thread, z prefetched, A_log in regs ----
#pragma unroll 1
    for (int p = 0; p < 2; ++p) {
        const int ch0 = p * 1024 + tid * 4;
        ushort4 zu[4];
#pragma unroll
        for (int j = 0; j < 4; ++j)
            zu[j] = *(const ushort4*)(xz + (size_t)(m0 + j) * 4096 + 2048 + ch0);
        float a2[4][16];
#pragma unroll
        for (int c = 0; c < 4; ++c) {
            const float4* ar = (const float4*)(Alog + (size_t)(ch0 + c) * 16);
#pragma unroll
            for (int n4 = 0; n4 < 4; ++n4) {
                float4 t4 = ar[n4];
                a2[c][n4 * 4 + 0] = -fexp(t4.x) * LOG2E;
                a2[c][n4 * 4 + 1] = -fexp(t4.y) * LOG2E;
                a2[c][n4 * 4 + 2] = -fexp(t4.z) * LOG2E;
                a2[c][n4 * 4 + 3] = -fexp(t4.w) * LOG2E;
            }
        }
        float4 dvv = *(const float4*)(Dv + ch0);
        float dv[4] = {dvv.x, dvv.y, dvv.z, dvv.w};
        const int c16 = ch0 >> 3, sub = ch0 & 7;
#pragma unroll
        for (int j = 0; j < 4; ++j) {
            const int m = m0 + j;
            float delta = sdg[j * 17];
            float Gr[16];
#pragma unroll
            for (int n = 0; n < 16; ++n) Gr[n] = sdg[j * 17 + 1 + n];
            ushort4 xu = *(const ushort4*)(sxc + j * 2048 + ((c16 ^ (j & 3)) * 8) + sub);
            float xcv[4] = {b2f(xu.x), b2f(xu.y), b2f(xu.z), b2f(xu.w)};
            float zv[4]  = {b2f(zu[j].x), b2f(zu[j].y), b2f(zu[j].z), b2f(zu[j].w)};
            unsigned short ov[4];
#pragma unroll
            for (int c = 0; c < 4; ++c) {
                float ssum = 0.f;
#pragma unroll
                for (int n = 0; n < 16; ++n)
                    ssum += Gr[n] * __builtin_amdgcn_exp2f(delta * a2[c][n]);
                float y = xcv[c] * (dv[c] + ssum);
                ov[c] = f2b(y * silu_f(zv[c]));
            }
            *(ushort4*)(y2 + (size_t)m * 2048 + ch0) = make_ushort4(ov[0], ov[1], ov[2], ov[3]);
        }
    }
}

// ---------- launch ----------
extern "C" void kernel_launch(void* const* d_in, const int* in_sizes, int n_in,
                              void* d_out, int out_size, void* d_ws, size_t ws_size,
                              hipStream_t stream) {
    const float* x      = (const float*)d_in[0];   // (2,2048,1024)
    const float* W_in   = (const float*)d_in[1];   // (4096,1024)
    const float* conv_w = (const float*)d_in[2];   // (2048,1,4)
    const float* W_x    = (const float*)d_in[3];   // (33,2048)
    const float* A_log  = (const float*)d_in[4];   // (2048,16)
    const float* Dvec   = (const float*)d_in[5];   // (2048,)
    const float* W_out  = (const float*)d_in[6];   // (1024,2048)

    char* ws = (char*)d_ws;
    unsigned short* xb  = (unsigned short*)(ws);              //  8,388,608  x bf16
    unsigned short* wib = (unsigned short*)(ws + 8388608);    //  8,388,608  W_in bf16
    unsigned short* wob = (unsigned short*)(ws + 16777216);   //  4,194,304  W_out bf16
    unsigned short* xz  = (unsigned short*)(ws + 20971520);   // 33,554,432  xz bf16 (4096x4096)
    unsigned short* y2  = (unsigned short*)(ws + 54525952);   // 16,777,216  y2 bf16 (4096x2048)
    unsigned short* wxb = (unsigned short*)(ws + 71303168);   //    196,608  Wx bf16 (48x2048 padded)

    cvt_all_k<<<10306, 256, 0, stream>>>(x, W_in, W_out, W_x, xb, wib, wob, wxb);
    // xz[m,i] = sum_h x[m,h] * W_in[i,h]
    gemm_bt<true><<<dim3(32, 32), 256, 0, stream>>>(xb, wib, xz, 4096, 1024);
    // conv+silu -> xproj -> delta/G -> SSM gate, all in one dispatch
    fused_mid_k<<<1024, 256, 0, stream>>>(xz, conv_w, wxb, A_log, Dvec, y2);
    // out[m,h] = sum_i y2[m,i] * W_out[h,i]
    gemm_bt_n64<<<dim3(16, 32), 256, 0, stream>>>(y2, wob, (float*)d_out, 1024, 2048);
}

// Round 8
// 215.484 us; speedup vs baseline: 1.4730x; 1.4730x over previous
//
#include <hip/hip_runtime.h>

#define LOG2E 1.4426950408889634f

// ---------- bf16 helpers (raw ushort representation) ----------
__device__ __forceinline__ float b2f(unsigned short u) {
    unsigned int v = ((unsigned int)u) << 16;
    return __builtin_bit_cast(float, v);
}
__device__ __forceinline__ unsigned short f2b(float f) {
    unsigned int u = __builtin_bit_cast(unsigned int, f);
    u += 0x7fffu + ((u >> 16) & 1u);   // round-to-nearest-even
    return (unsigned short)(u >> 16);
}
__device__ __forceinline__ float fexp(float x) {           // e^x
    return __builtin_amdgcn_exp2f(x * LOG2E);
}
__device__ __forceinline__ float silu_f(float x) {
    return x * __builtin_amdgcn_rcpf(1.0f + fexp(-x));
}
__device__ __forceinline__ unsigned short u4get(ushort4 v, int c) {
    return c == 0 ? v.x : c == 1 ? v.y : c == 2 ? v.z : v.w;   // folds under unroll
}

// async global->LDS 16B per lane; lptr must be wave-uniform (dest = base + lane*16)
typedef const __attribute__((address_space(1))) unsigned int* gas_t;
typedef __attribute__((address_space(3))) unsigned int* las_t;
__device__ __forceinline__ void gl2lds16(const unsigned short* g, unsigned short* l) {
    __builtin_amdgcn_global_load_lds((gas_t)(const void*)g, (las_t)(void*)l, 16, 0, 0);
}

// ---------- fused fp32 -> bf16 cast (4 arrays) + A2 = -exp(A_log)*log2e ----------
// grid: 4096 x | 4096 W_in | 2048 W_out | 66 W_x | 32 Alog->A2  (all exact fits)
__global__ __launch_bounds__(256) void cvt_all_k(const float* __restrict__ x,
                                                 const float* __restrict__ W_in,
                                                 const float* __restrict__ W_out,
                                                 const float* __restrict__ W_x,
                                                 const float* __restrict__ Alog,
                                                 unsigned short* __restrict__ xb,
                                                 unsigned short* __restrict__ wib,
                                                 unsigned short* __restrict__ wob,
                                                 unsigned short* __restrict__ wxb,
                                                 float* __restrict__ A2) {
    int b = blockIdx.x;
    if (b >= 10306) {                    // A_log -> A2 (float out)
        int i = (b - 10306) * 256 + threadIdx.x;
        float4 v = ((const float4*)Alog)[i];
        ((float4*)A2)[i] = make_float4(-fexp(v.x) * LOG2E, -fexp(v.y) * LOG2E,
                                       -fexp(v.z) * LOG2E, -fexp(v.w) * LOG2E);
        return;
    }
    const float* src;
    unsigned short* dst;
    if (b < 4096)       { src = x;     dst = xb;  }
    else if (b < 8192)  { src = W_in;  dst = wib; b -= 4096; }
    else if (b < 10240) { src = W_out; dst = wob; b -= 8192; }
    else                { src = W_x;   dst = wxb; b -= 10240; }
    int i = b * 256 + threadIdx.x;
    float4 v = ((const float4*)src)[i];
    *(ushort4*)(dst + (size_t)i * 4) = make_ushort4(f2b(v.x), f2b(v.y), f2b(v.z), f2b(v.w));
}

// ---------- bf16 MFMA GEMM: C[M,N] = A[M,K] * B[N,K]^T ----------
// 128x128 tile, BK=64, global_load_lds w=16, XOR-swizzled (conflicts=0, verified R3).
typedef __bf16 bf16x8 __attribute__((ext_vector_type(8)));
typedef float  fx4    __attribute__((ext_vector_type(4)));
typedef int    ix4    __attribute__((ext_vector_type(4)));
union FragU { ix4 i; bf16x8 b; };

template <bool OUT_BF16>
__global__ __launch_bounds__(256) void gemm_bt(const unsigned short* __restrict__ A,
                                               const unsigned short* __restrict__ B,
                                               void* __restrict__ C, int N, int K) {
    __shared__ __align__(16) unsigned short sA[128 * 64];
    __shared__ __align__(16) unsigned short sB[128 * 64];
    const int tid  = threadIdx.x;
    const int lane = tid & 63, wave = tid >> 6;
    const int bm = blockIdx.y * 128, bn = blockIdx.x * 128;
    const int wm = (wave >> 1) * 64, wn = (wave & 1) * 64;
    const int row16 = lane & 15, quad = lane >> 4;
    const int srow = lane >> 3;
    const int sc16 = (lane & 7) ^ srow;
    const unsigned short* gA = A + (size_t)(bm + wave * 32 + srow) * K + sc16 * 8;
    const unsigned short* gB = B + (size_t)(bn + wave * 32 + srow) * K + sc16 * 8;
    unsigned short* lA = sA + (wave * 4) * 512;   // wave-uniform
    unsigned short* lB = sB + (wave * 4) * 512;
    fx4 acc[4][4] = {};

    for (int kt = 0; kt < K; kt += 64) {
#pragma unroll
        for (int it = 0; it < 4; ++it) {
            gl2lds16(gA + (size_t)it * 8 * K + kt, lA + it * 512);
            gl2lds16(gB + (size_t)it * 8 * K + kt, lB + it * 512);
        }
        __syncthreads();
#pragma unroll
        for (int kk = 0; kk < 64; kk += 32) {
            FragU af[4], bf[4];
#pragma unroll
            for (int t = 0; t < 4; ++t) {
                int ra = wm + t * 16 + row16;
                af[t].i = *(const ix4*)(sA + ra * 64 + ((quad + (kk >> 3)) ^ (ra & 7)) * 8);
            }
#pragma unroll
            for (int t = 0; t < 4; ++t) {
                int rb = wn + t * 16 + row16;
                bf[t].i = *(const ix4*)(sB + rb * 64 + ((quad + (kk >> 3)) ^ (rb & 7)) * 8);
            }
#pragma unroll
            for (int tm = 0; tm < 4; ++tm)
#pragma unroll
                for (int tn = 0; tn < 4; ++tn)
                    acc[tm][tn] = __builtin_amdgcn_mfma_f32_16x16x32_bf16(
                        af[tm].b, bf[tn].b, acc[tm][tn], 0, 0, 0);
        }
        __syncthreads();
    }
#pragma unroll
    for (int tm = 0; tm < 4; ++tm) {
        int row0 = bm + wm + tm * 16 + quad * 4;
#pragma unroll
        for (int tn = 0; tn < 4; ++tn) {
            int col = bn + wn + tn * 16 + row16;
#pragma unroll
            for (int r = 0; r < 4; ++r) {
                float v = acc[tm][tn][r];
                if (OUT_BF16)
                    ((unsigned short*)C)[(size_t)(row0 + r) * N + col] = f2b(v);
                else
                    ((float*)C)[(size_t)(row0 + r) * N + col] = v;
            }
        }
    }
}

// ---------- narrow GEMM for C[M,1024]: 128x64 tile, 512 blocks = 2/CU ----------
__global__ __launch_bounds__(256) void gemm_bt_n64(const unsigned short* __restrict__ A,
                                                   const unsigned short* __restrict__ B,
                                                   float* __restrict__ C, int N, int K) {
    __shared__ __align__(16) unsigned short sA[128 * 64];
    __shared__ __align__(16) unsigned short sB[64 * 64];
    const int tid  = threadIdx.x;
    const int lane = tid & 63, wave = tid >> 6;
    const int bm = blockIdx.y * 128, bn = blockIdx.x * 64;
    const int wm = wave * 32;
    const int row16 = lane & 15, quad = lane >> 4;
    const int srow = lane >> 3;
    const int sc16 = (lane & 7) ^ srow;
    const unsigned short* gA = A + (size_t)(bm + wave * 32 + srow) * K + sc16 * 8;
    const unsigned short* gB = B + (size_t)(bn + wave * 16 + srow) * K + sc16 * 8;
    unsigned short* lA = sA + (wave * 4) * 512;
    unsigned short* lB = sB + (wave * 2) * 512;
    fx4 acc[2][4] = {};

    for (int kt = 0; kt < K; kt += 64) {
#pragma unroll
        for (int it = 0; it < 4; ++it)
            gl2lds16(gA + (size_t)it * 8 * K + kt, lA + it * 512);
#pragma unroll
        for (int it = 0; it < 2; ++it)
            gl2lds16(gB + (size_t)it * 8 * K + kt, lB + it * 512);
        __syncthreads();
#pragma unroll
        for (int kk = 0; kk < 64; kk += 32) {
            FragU af[2], bf[4];
#pragma unroll
            for (int t = 0; t < 2; ++t) {
                int ra = wm + t * 16 + row16;
                af[t].i = *(const ix4*)(sA + ra * 64 + ((quad + (kk >> 3)) ^ (ra & 7)) * 8);
            }
#pragma unroll
            for (int t = 0; t < 4; ++t) {
                int rb = t * 16 + row16;
                bf[t].i = *(const ix4*)(sB + rb * 64 + ((quad + (kk >> 3)) ^ (rb & 7)) * 8);
            }
#pragma unroll
            for (int tm = 0; tm < 2; ++tm)
#pragma unroll
                for (int tn = 0; tn < 4; ++tn)
                    acc[tm][tn] = __builtin_amdgcn_mfma_f32_16x16x32_bf16(
                        af[tm].b, bf[tn].b, acc[tm][tn], 0, 0, 0);
        }
        __syncthreads();
    }
#pragma unroll
    for (int tm = 0; tm < 2; ++tm) {
        int row0 = bm + wm + tm * 16 + quad * 4;
#pragma unroll
        for (int tn = 0; tn < 4; ++tn) {
            int col = bn + tn * 16 + row16;
#pragma unroll
            for (int r = 0; r < 4; ++r)
                C[(size_t)(row0 + r) * N + col] = acc[tm][tn][r];
        }
    }
}

// ---------- A: conv+silu -> LDS xc -> xproj MFMA -> dgp[m][17] ----------
// grid 512 x 256 thr; 8-row tile. Window preloaded as raw ushort4 (22 VGPRs,
// no float expansion -> no spill, R7 lesson). LDS ~45 KB -> 3 blocks/CU.
__global__ __launch_bounds__(256) void conv_xproj_k(const unsigned short* __restrict__ xz,
                                                    const float* __restrict__ cw,
                                                    const unsigned short* __restrict__ wxb,
                                                    float* __restrict__ dg) {
    __shared__ __align__(16) unsigned short sxc[8 * 2048];    // 32 KB
    __shared__ float sX[4][16][49];                            // 12.5 KB
    const int tid  = threadIdx.x;
    const int lane = tid & 63, wave = tid >> 6;
    const int row16 = lane & 15, quad = lane >> 4;
    const int m0 = blockIdx.x * 8, s0 = m0 & 2047;

    // ---- phase 1: conv(K=4, causal) + silu, 8 rows x 2048 ch ----
    {
        ushort4 ua[11], ub[11];
#pragma unroll
        for (int t = 0; t < 11; ++t) {
            int mr = (s0 - 3 + t >= 0) ? (m0 - 3 + t) : m0;   // clamped, zeroed below
            const unsigned short* p = xz + (size_t)mr * 4096 + tid * 8;
            ua[t] = *(const ushort4*)p;
            ub[t] = *(const ushort4*)(p + 4);
        }
        float w[8][4];
        const float4* cw4 = (const float4*)cw;
#pragma unroll
        for (int c = 0; c < 8; ++c) {
            float4 t4 = cw4[tid * 8 + c];
            w[c][0] = t4.x; w[c][1] = t4.y; w[c][2] = t4.z; w[c][3] = t4.w;
        }
#pragma unroll
        for (int t = 0; t < 3; ++t)
            if (s0 - 3 + t < 0) { ua[t] = make_ushort4(0, 0, 0, 0); ub[t] = make_ushort4(0, 0, 0, 0); }
#pragma unroll
        for (int j = 0; j < 8; ++j) {
            float acc[8] = {0, 0, 0, 0, 0, 0, 0, 0};
#pragma unroll
            for (int k = 0; k < 4; ++k) {
                ushort4 a = ua[j + k], b = ub[j + k];
                float v[8] = {b2f(a.x), b2f(a.y), b2f(a.z), b2f(a.w),
                              b2f(b.x), b2f(b.y), b2f(b.z), b2f(b.w)};
#pragma unroll
                for (int c = 0; c < 8; ++c) acc[c] += v[c] * w[c][k];
            }
            unsigned short* q = sxc + j * 2048 + ((tid ^ (j & 7)) * 8);
            *(ushort4*)q       = make_ushort4(f2b(silu_f(acc[0])), f2b(silu_f(acc[1])),
                                              f2b(silu_f(acc[2])), f2b(silu_f(acc[3])));
            *(ushort4*)(q + 4) = make_ushort4(f2b(silu_f(acc[4])), f2b(silu_f(acc[5])),
                                              f2b(silu_f(acc[6])), f2b(silu_f(acc[7])));
        }
    }
    __syncthreads();

    // ---- phase 2: xproj = xc @ Wx^T (N=33 pad 48); wave = K-quarter; A from LDS ----
    // A rows 8..15 duplicate rows 0..7 (row16&7); their D rows are discarded.
    {
        fx4 acc[3] = {};
        const unsigned short* bp = wxb + (size_t)row16 * 2048 + wave * 512 + quad * 8;
        const int arow = row16 & 7;
        const int cbase = wave * 64 + quad;
#pragma unroll 4
        for (int kk = 0; kk < 512; kk += 32) {
            FragU a, b0, b1, b2;
            int c16 = cbase + (kk >> 3);
            a.i  = *(const ix4*)(sxc + arow * 2048 + ((c16 ^ arow) * 8));
            b0.i = *(const ix4*)(bp + kk);
            b1.i = *(const ix4*)(bp + 16 * 2048 + kk);
            b2.i = *(const ix4*)(bp + 32 * 2048 + kk);
            acc[0] = __builtin_amdgcn_mfma_f32_16x16x32_bf16(a.b, b0.b, acc[0], 0, 0, 0);
            acc[1] = __builtin_amdgcn_mfma_f32_16x16x32_bf16(a.b, b1.b, acc[1], 0, 0, 0);
            acc[2] = __builtin_amdgcn_mfma_f32_16x16x32_bf16(a.b, b2.b, acc[2], 0, 0, 0);
        }
#pragma unroll
        for (int t = 0; t < 3; ++t)
#pragma unroll
            for (int r = 0; r < 4; ++r)
                sX[wave][quad * 4 + r][t * 16 + row16] = acc[t][r];
    }
    __syncthreads();
    for (int idx = tid; idx < 136; idx += 256) {
        int rr = idx / 17, q = idx - rr * 17;
        float o;
        if (q == 0) {
            float v = sX[0][rr][0] + sX[1][rr][0] + sX[2][rr][0] + sX[3][rr][0];
            o = (v > 20.f) ? v : log1pf(fexp(v));          // softplus(delta_raw)
        } else {
            float bs = sX[0][rr][q]      + sX[1][rr][q]      + sX[2][rr][q]      + sX[3][rr][q];
            float cs = sX[0][rr][q + 16] + sX[1][rr][q + 16] + sX[2][rr][q + 16] + sX[3][rr][q + 16];
            o = bs * cs;                                   // G[n] = B[n]*C[n]
        }
        dg[(size_t)(m0 + rr) * 17 + q] = o;
    }
}

// ---------- B: conv (recomputed per-thread-channel) + SSM + gate -> y2 ----------
// grid (2, 512) x 256 thr; thread owns 4 channels x 8 rows. Conv output stays in
// registers -> no transpose, no LDS xc, no barrier in the hot path.
__global__ __launch_bounds__(256, 2) void conv_ssm_k(const unsigned short* __restrict__ xz,
                                                     const float* __restrict__ cw,
                                                     const float* __restrict__ dg,
                                                     const float* __restrict__ A2,
                                                     const float* __restrict__ Dv,
                                                     unsigned short* __restrict__ y2) {
    __shared__ float sdg[8 * 17];
    const int tid = threadIdx.x;
    const int m0 = blockIdx.y * 8, s0 = m0 & 2047;
    const int ch0 = blockIdx.x * 1024 + tid * 4;
    if (tid < 136) sdg[tid] = dg[(size_t)m0 * 17 + tid];

    // preload conv window (11 rows x 4 ch) and z (8 rows x 4 ch) — all independent
    ushort4 uw[11];
#pragma unroll
    for (int t = 0; t < 11; ++t) {
        int mr = (s0 - 3 + t >= 0) ? (m0 - 3 + t) : m0;
        uw[t] = *(const ushort4*)(xz + (size_t)mr * 4096 + ch0);
    }
    ushort4 zu[8];
#pragma unroll
    for (int j = 0; j < 8; ++j)
        zu[j] = *(const ushort4*)(xz + (size_t)(m0 + j) * 4096 + 2048 + ch0);
    float w[4][4];
    const float4* cw4 = (const float4*)cw;
#pragma unroll
    for (int c = 0; c < 4; ++c) {
        float4 t4 = cw4[ch0 + c];
        w[c][0] = t4.x; w[c][1] = t4.y; w[c][2] = t4.z; w[c][3] = t4.w;
    }
    float a2[4][16];
#pragma unroll
    for (int c = 0; c < 4; ++c) {
        const float4* ar = (const float4*)(A2 + (size_t)(ch0 + c) * 16);
#pragma unroll
        for (int n4 = 0; n4 < 4; ++n4) {
            float4 t4 = ar[n4];
            a2[c][n4 * 4 + 0] = t4.x; a2[c][n4 * 4 + 1] = t4.y;
            a2[c][n4 * 4 + 2] = t4.z; a2[c][n4 * 4 + 3] = t4.w;
        }
    }
    float4 dvv = *(const float4*)(Dv + ch0);
    float dv[4] = {dvv.x, dvv.y, dvv.z, dvv.w};
#pragma unroll
    for (int t = 0; t < 3; ++t)
        if (s0 - 3 + t < 0) uw[t] = make_ushort4(0, 0, 0, 0);
    __syncthreads();

#pragma unroll
    for (int j = 0; j < 8; ++j) {
        float delta = sdg[j * 17];
        float Gr[16];
#pragma unroll
        for (int n = 0; n < 16; ++n) Gr[n] = sdg[j * 17 + 1 + n];
        unsigned short ov[4];
#pragma unroll
        for (int c = 0; c < 4; ++c) {
            float acc = 0.f;
#pragma unroll
            for (int k = 0; k < 4; ++k)
                acc += b2f(u4get(uw[j + k], c)) * w[c][k];
            float xc = silu_f(acc);
            float ssum = 0.f;
#pragma unroll
            for (int n = 0; n < 16; ++n)
                ssum += Gr[n] * __builtin_amdgcn_exp2f(delta * a2[c][n]);
            float y = xc * (dv[c] + ssum);
            ov[c] = f2b(y * silu_f(b2f(u4get(zu[j], c))));
        }
        *(ushort4*)(y2 + (size_t)(m0 + j) * 2048 + ch0) = make_ushort4(ov[0], ov[1], ov[2], ov[3]);
    }
}

// ---------- launch ----------
extern "C" void kernel_launch(void* const* d_in, const int* in_sizes, int n_in,
                              void* d_out, int out_size, void* d_ws, size_t ws_size,
                              hipStream_t stream) {
    const float* x      = (const float*)d_in[0];   // (2,2048,1024)
    const float* W_in   = (const float*)d_in[1];   // (4096,1024)
    const float* conv_w = (const float*)d_in[2];   // (2048,1,4)
    const float* W_x    = (const float*)d_in[3];   // (33,2048)
    const float* A_log  = (const float*)d_in[4];   // (2048,16)
    const float* Dvec   = (const float*)d_in[5];   // (2048,)
    const float* W_out  = (const float*)d_in[6];   // (1024,2048)

    char* ws = (char*)d_ws;
    unsigned short* xb  = (unsigned short*)(ws);              //  8,388,608  x bf16
    unsigned short* wib = (unsigned short*)(ws + 8388608);    //  8,388,608  W_in bf16
    unsigned short* wob = (unsigned short*)(ws + 16777216);   //  4,194,304  W_out bf16
    unsigned short* xz  = (unsigned short*)(ws + 20971520);   // 33,554,432  xz bf16 (4096x4096)
    unsigned short* y2  = (unsigned short*)(ws + 54525952);   // 16,777,216  y2 bf16 (4096x2048)
    unsigned short* wxb = (unsigned short*)(ws + 71303168);   //    196,608  Wx bf16 (48x2048 padded)
    float*          dgp = (float*)        (ws + 71499776);    //    278,528  delta+G (4096x17)
    float*          a2p = (float*)        (ws + 71778304);    //    131,072  A2 (2048x16)

    cvt_all_k<<<10338, 256, 0, stream>>>(x, W_in, W_out, W_x, A_log, xb, wib, wob, wxb, a2p);
    // xz[m,i] = sum_h x[m,h] * W_in[i,h]
    gemm_bt<true><<<dim3(32, 32), 256, 0, stream>>>(xb, wib, xz, 4096, 1024);
    // A: conv+silu -> xproj -> delta/G
    conv_xproj_k<<<512, 256, 0, stream>>>(xz, conv_w, wxb, dgp);
    // B: conv (per-thread-channel) + SSM + gate -> y2
    conv_ssm_k<<<dim3(2, 512), 256, 0, stream>>>(xz, conv_w, dgp, a2p, Dvec, y2);
    // out[m,h] = sum_i y2[m,i] * W_out[h,i]
    gemm_bt_n64<<<dim3(16, 32), 256, 0, stream>>>(y2, wob, (float*)d_out, 1024, 2048);
}

// Round 9
// 207.438 us; speedup vs baseline: 1.5301x; 1.0388x over previous
//
#include <hip/hip_runtime.h>

#define LOG2E 1.4426950408889634f

// ---------- bf16 helpers (raw ushort representation) ----------
__device__ __forceinline__ float b2f(unsigned short u) {
    unsigned int v = ((unsigned int)u) << 16;
    return __builtin_bit_cast(float, v);
}
__device__ __forceinline__ unsigned short f2b(float f) {
    unsigned int u = __builtin_bit_cast(unsigned int, f);
    u += 0x7fffu + ((u >> 16) & 1u);   // round-to-nearest-even
    return (unsigned short)(u >> 16);
}
__device__ __forceinline__ float fexp(float x) {           // e^x
    return __builtin_amdgcn_exp2f(x * LOG2E);
}
__device__ __forceinline__ float silu_f(float x) {
    return x * __builtin_amdgcn_rcpf(1.0f + fexp(-x));
}
__device__ __forceinline__ unsigned short u4get(ushort4 v, int c) {
    return c == 0 ? v.x : c == 1 ? v.y : c == 2 ? v.z : v.w;   // folds under unroll
}

// async global->LDS 16B per lane; lptr must be wave-uniform (dest = base + lane*16)
typedef const __attribute__((address_space(1))) unsigned int* gas_t;
typedef __attribute__((address_space(3))) unsigned int* las_t;
__device__ __forceinline__ void gl2lds16(const unsigned short* g, unsigned short* l) {
    __builtin_amdgcn_global_load_lds((gas_t)(const void*)g, (las_t)(void*)l, 16, 0, 0);
}

typedef __bf16 bf16x8 __attribute__((ext_vector_type(8)));
typedef float  fx4    __attribute__((ext_vector_type(4)));
typedef int    ix4    __attribute__((ext_vector_type(4)));
union FragU { ix4 i; bf16x8 b; };

// ---------- cast x + W_in only (must precede GEMM1) ----------
__global__ __launch_bounds__(256) void cast_xw_k(const float* __restrict__ x,
                                                 const float* __restrict__ W_in,
                                                 unsigned short* __restrict__ xb,
                                                 unsigned short* __restrict__ wib) {
    int b = blockIdx.x;
    const float* src = (b < 4096) ? x : W_in;
    unsigned short* dst = (b < 4096) ? xb : wib;
    int i = (b & 4095) * 256 + threadIdx.x;
    float4 v = ((const float4*)src)[i];
    *(ushort4*)(dst + (size_t)i * 4) = make_ushort4(f2b(v.x), f2b(v.y), f2b(v.z), f2b(v.w));
}

// ---------- GEMM1 (xz = xb @ wib^T, 4096x4096x1024) + folded small casts ----------
// blocks 0..2145: cast W_out/W_x/A2 (no dependency on gemm part);
// blocks 2146..3169: 128x128 gemm tiles (m97 structure, XOR swizzle, conflicts=0).
__global__ __launch_bounds__(256) void gemm1_cast_k(const unsigned short* __restrict__ A,
                                                    const unsigned short* __restrict__ B,
                                                    unsigned short* __restrict__ C,
                                                    const float* __restrict__ W_out,
                                                    const float* __restrict__ W_x,
                                                    const float* __restrict__ Alog,
                                                    unsigned short* __restrict__ wob,
                                                    unsigned short* __restrict__ wxb,
                                                    float* __restrict__ A2) {
    const int bid = blockIdx.x;
    if (bid < 2146) {
        if (bid < 2048) {                    // W_out -> wob (bf16)
            int i = bid * 256 + threadIdx.x;
            float4 v = ((const float4*)W_out)[i];
            *(ushort4*)(wob + (size_t)i * 4) = make_ushort4(f2b(v.x), f2b(v.y), f2b(v.z), f2b(v.w));
        } else if (bid < 2114) {             // W_x -> wxb (bf16)
            int i = (bid - 2048) * 256 + threadIdx.x;
            float4 v = ((const float4*)W_x)[i];
            *(ushort4*)(wxb + (size_t)i * 4) = make_ushort4(f2b(v.x), f2b(v.y), f2b(v.z), f2b(v.w));
        } else {                             // A_log -> A2 = -exp(A_log)*log2e (fp32)
            int i = (bid - 2114) * 256 + threadIdx.x;
            float4 v = ((const float4*)Alog)[i];
            ((float4*)A2)[i] = make_float4(-fexp(v.x) * LOG2E, -fexp(v.y) * LOG2E,
                                           -fexp(v.z) * LOG2E, -fexp(v.w) * LOG2E);
        }
        return;
    }
    const int g = bid - 2146;
    const int N = 4096, K = 1024;
    __shared__ __align__(16) unsigned short sA[128 * 64];
    __shared__ __align__(16) unsigned short sB[128 * 64];
    const int tid  = threadIdx.x;
    const int lane = tid & 63, wave = tid >> 6;
    const int bm = (g >> 5) * 128, bn = (g & 31) * 128;
    const int wm = (wave >> 1) * 64, wn = (wave & 1) * 64;
    const int row16 = lane & 15, quad = lane >> 4;
    const int srow = lane >> 3;
    const int sc16 = (lane & 7) ^ srow;
    const unsigned short* gA = A + (size_t)(bm + wave * 32 + srow) * K + sc16 * 8;
    const unsigned short* gB = B + (size_t)(bn + wave * 32 + srow) * K + sc16 * 8;
    unsigned short* lA = sA + (wave * 4) * 512;   // wave-uniform
    unsigned short* lB = sB + (wave * 4) * 512;
    fx4 acc[4][4] = {};

    for (int kt = 0; kt < K; kt += 64) {
#pragma unroll
        for (int it = 0; it < 4; ++it) {
            gl2lds16(gA + (size_t)it * 8 * K + kt, lA + it * 512);
            gl2lds16(gB + (size_t)it * 8 * K + kt, lB + it * 512);
        }
        __syncthreads();
#pragma unroll
        for (int kk = 0; kk < 64; kk += 32) {
            FragU af[4], bf[4];
#pragma unroll
            for (int t = 0; t < 4; ++t) {
                int ra = wm + t * 16 + row16;
                af[t].i = *(const ix4*)(sA + ra * 64 + ((quad + (kk >> 3)) ^ (ra & 7)) * 8);
            }
#pragma unroll
            for (int t = 0; t < 4; ++t) {
                int rb = wn + t * 16 + row16;
                bf[t].i = *(const ix4*)(sB + rb * 64 + ((quad + (kk >> 3)) ^ (rb & 7)) * 8);
            }
#pragma unroll
            for (int tm = 0; tm < 4; ++tm)
#pragma unroll
                for (int tn = 0; tn < 4; ++tn)
                    acc[tm][tn] = __builtin_amdgcn_mfma_f32_16x16x32_bf16(
                        af[tm].b, bf[tn].b, acc[tm][tn], 0, 0, 0);
        }
        __syncthreads();
    }
#pragma unroll
    for (int tm = 0; tm < 4; ++tm) {
        int row0 = bm + wm + tm * 16 + quad * 4;
#pragma unroll
        for (int tn = 0; tn < 4; ++tn) {
            int col = bn + wn + tn * 16 + row16;
#pragma unroll
            for (int r = 0; r < 4; ++r)
                C[(size_t)(row0 + r) * N + col] = f2b(acc[tm][tn][r]);
        }
    }
}

// ---------- GEMM3: C[4096,1024] fp32 = y2 @ wob^T; 64x64 tiles, 1024 blocks = 4/CU ----------
// R9: smaller tile for occupancy — 4 waves stacked in M (wave tile 16x64, 1x4 frags),
// MFMA:stage ratio 8:2 per iter (vs 16:6 in the 128x64 version), LDS 16 KB.
__global__ __launch_bounds__(256) void gemm_bt_64(const unsigned short* __restrict__ A,
                                                  const unsigned short* __restrict__ B,
                                                  float* __restrict__ C, int N, int K) {
    __shared__ __align__(16) unsigned short sA[64 * 64];
    __shared__ __align__(16) unsigned short sB[64 * 64];
    const int tid  = threadIdx.x;
    const int lane = tid & 63, wave = tid >> 6;
    const int bm = blockIdx.y * 64, bn = blockIdx.x * 64;
    const int wm = wave * 16;
    const int row16 = lane & 15, quad = lane >> 4;
    const int srow = lane >> 3;
    const int sc16 = (lane & 7) ^ srow;
    const unsigned short* gA = A + (size_t)(bm + wave * 16 + srow) * K + sc16 * 8;
    const unsigned short* gB = B + (size_t)(bn + wave * 16 + srow) * K + sc16 * 8;
    unsigned short* lA = sA + (wave * 2) * 512;   // 2 A-chunks / wave
    unsigned short* lB = sB + (wave * 2) * 512;   // 2 B-chunks / wave
    fx4 acc[4] = {};

    for (int kt = 0; kt < K; kt += 64) {
#pragma unroll
        for (int it = 0; it < 2; ++it) {
            gl2lds16(gA + (size_t)it * 8 * K + kt, lA + it * 512);
            gl2lds16(gB + (size_t)it * 8 * K + kt, lB + it * 512);
        }
        __syncthreads();
#pragma unroll
        for (int kk = 0; kk < 64; kk += 32) {
            FragU af, bf[4];
            int ra = wm + row16;
            af.i = *(const ix4*)(sA + ra * 64 + ((quad + (kk >> 3)) ^ (ra & 7)) * 8);
#pragma unroll
            for (int t = 0; t < 4; ++t) {
                int rb = t * 16 + row16;
                bf[t].i = *(const ix4*)(sB + rb * 64 + ((quad + (kk >> 3)) ^ (rb & 7)) * 8);
            }
#pragma unroll
            for (int tn = 0; tn < 4; ++tn)
                acc[tn] = __builtin_amdgcn_mfma_f32_16x16x32_bf16(af.b, bf[tn].b, acc[tn], 0, 0, 0);
        }
        __syncthreads();
    }
    const int row0 = bm + wm + quad * 4;
#pragma unroll
    for (int tn = 0; tn < 4; ++tn) {
        int col = bn + tn * 16 + row16;
#pragma unroll
        for (int r = 0; r < 4; ++r)
            C[(size_t)(row0 + r) * N + col] = acc[tn][r];
    }
}

// ---------- A: conv+silu -> LDS xc -> xproj MFMA -> dgp[m][17] ----------
// grid 512 x 256 thr; 8-row tile (unchanged from R8 — verified working).
__global__ __launch_bounds__(256) void conv_xproj_k(const unsigned short* __restrict__ xz,
                                                    const float* __restrict__ cw,
                                                    const unsigned short* __restrict__ wxb,
                                                    float* __restrict__ dg) {
    __shared__ __align__(16) unsigned short sxc[8 * 2048];    // 32 KB
    __shared__ float sX[4][16][49];                            // 12.5 KB
    const int tid  = threadIdx.x;
    const int lane = tid & 63, wave = tid >> 6;
    const int row16 = lane & 15, quad = lane >> 4;
    const int m0 = blockIdx.x * 8, s0 = m0 & 2047;

    // ---- phase 1: conv(K=4, causal) + silu, 8 rows x 2048 ch ----
    {
        ushort4 ua[11], ub[11];
#pragma unroll
        for (int t = 0; t < 11; ++t) {
            int mr = (s0 - 3 + t >= 0) ? (m0 - 3 + t) : m0;   // clamped, zeroed below
            const unsigned short* p = xz + (size_t)mr * 4096 + tid * 8;
            ua[t] = *(const ushort4*)p;
            ub[t] = *(const ushort4*)(p + 4);
        }
        float w[8][4];
        const float4* cw4 = (const float4*)cw;
#pragma unroll
        for (int c = 0; c < 8; ++c) {
            float4 t4 = cw4[tid * 8 + c];
            w[c][0] = t4.x; w[c][1] = t4.y; w[c][2] = t4.z; w[c][3] = t4.w;
        }
#pragma unroll
        for (int t = 0; t < 3; ++t)
            if (s0 - 3 + t < 0) { ua[t] = make_ushort4(0, 0, 0, 0); ub[t] = make_ushort4(0, 0, 0, 0); }
#pragma unroll
        for (int j = 0; j < 8; ++j) {
            float acc[8] = {0, 0, 0, 0, 0, 0, 0, 0};
#pragma unroll
            for (int k = 0; k < 4; ++k) {
                ushort4 a = ua[j + k], b = ub[j + k];
                float v[8] = {b2f(a.x), b2f(a.y), b2f(a.z), b2f(a.w),
                              b2f(b.x), b2f(b.y), b2f(b.z), b2f(b.w)};
#pragma unroll
                for (int c = 0; c < 8; ++c) acc[c] += v[c] * w[c][k];
            }
            unsigned short* q = sxc + j * 2048 + ((tid ^ (j & 7)) * 8);
            *(ushort4*)q       = make_ushort4(f2b(silu_f(acc[0])), f2b(silu_f(acc[1])),
                                              f2b(silu_f(acc[2])), f2b(silu_f(acc[3])));
            *(ushort4*)(q + 4) = make_ushort4(f2b(silu_f(acc[4])), f2b(silu_f(acc[5])),
                                              f2b(silu_f(acc[6])), f2b(silu_f(acc[7])));
        }
    }
    __syncthreads();

    // ---- phase 2: xproj = xc @ Wx^T (N=33 pad 48); wave = K-quarter; A from LDS ----
    {
        fx4 acc[3] = {};
        const unsigned short* bp = wxb + (size_t)row16 * 2048 + wave * 512 + quad * 8;
        const int arow = row16 & 7;
        const int cbase = wave * 64 + quad;
#pragma unroll 4
        for (int kk = 0; kk < 512; kk += 32) {
            FragU a, b0, b1, b2;
            int c16 = cbase + (kk >> 3);
            a.i  = *(const ix4*)(sxc + arow * 2048 + ((c16 ^ arow) * 8));
            b0.i = *(const ix4*)(bp + kk);
            b1.i = *(const ix4*)(bp + 16 * 2048 + kk);
            b2.i = *(const ix4*)(bp + 32 * 2048 + kk);
            acc[0] = __builtin_amdgcn_mfma_f32_16x16x32_bf16(a.b, b0.b, acc[0], 0, 0, 0);
            acc[1] = __builtin_amdgcn_mfma_f32_16x16x32_bf16(a.b, b1.b, acc[1], 0, 0, 0);
            acc[2] = __builtin_amdgcn_mfma_f32_16x16x32_bf16(a.b, b2.b, acc[2], 0, 0, 0);
        }
#pragma unroll
        for (int t = 0; t < 3; ++t)
#pragma unroll
            for (int r = 0; r < 4; ++r)
                sX[wave][quad * 4 + r][t * 16 + row16] = acc[t][r];
    }
    __syncthreads();
    for (int idx = tid; idx < 136; idx += 256) {
        int rr = idx / 17, q = idx - rr * 17;
        float o;
        if (q == 0) {
            float v = sX[0][rr][0] + sX[1][rr][0] + sX[2][rr][0] + sX[3][rr][0];
            o = (v > 20.f) ? v : log1pf(fexp(v));          // softplus(delta_raw)
        } else {
            float bs = sX[0][rr][q]      + sX[1][rr][q]      + sX[2][rr][q]      + sX[3][rr][q];
            float cs = sX[0][rr][q + 16] + sX[1][rr][q + 16] + sX[2][rr][q + 16] + sX[3][rr][q + 16];
            o = bs * cs;                                   // G[n] = B[n]*C[n]
        }
        dg[(size_t)(m0 + rr) * 17 + q] = o;
    }
}

// ---------- B: conv (recomputed per-thread-channel) + SSM + gate -> y2 ----------
// grid (2, 512) x 256 thr (unchanged from R8 — verified working).
__global__ __launch_bounds__(256, 2) void conv_ssm_k(const unsigned short* __restrict__ xz,
                                                     const float* __restrict__ cw,
                                                     const float* __restrict__ dg,
                                                     const float* __restrict__ A2,
                                                     const float* __restrict__ Dv,
                                                     unsigned short* __restrict__ y2) {
    __shared__ float sdg[8 * 17];
    const int tid = threadIdx.x;
    const int m0 = blockIdx.y * 8, s0 = m0 & 2047;
    const int ch0 = blockIdx.x * 1024 + tid * 4;
    if (tid < 136) sdg[tid] = dg[(size_t)m0 * 17 + tid];

    ushort4 uw[11];
#pragma unroll
    for (int t = 0; t < 11; ++t) {
        int mr = (s0 - 3 + t >= 0) ? (m0 - 3 + t) : m0;
        uw[t] = *(const ushort4*)(xz + (size_t)mr * 4096 + ch0);
    }
    ushort4 zu[8];
#pragma unroll
    for (int j = 0; j < 8; ++j)
        zu[j] = *(const ushort4*)(xz + (size_t)(m0 + j) * 4096 + 2048 + ch0);
    float w[4][4];
    const float4* cw4 = (const float4*)cw;
#pragma unroll
    for (int c = 0; c < 4; ++c) {
        float4 t4 = cw4[ch0 + c];
        w[c][0] = t4.x; w[c][1] = t4.y; w[c][2] = t4.z; w[c][3] = t4.w;
    }
    float a2[4][16];
#pragma unroll
    for (int c = 0; c < 4; ++c) {
        const float4* ar = (const float4*)(A2 + (size_t)(ch0 + c) * 16);
#pragma unroll
        for (int n4 = 0; n4 < 4; ++n4) {
            float4 t4 = ar[n4];
            a2[c][n4 * 4 + 0] = t4.x; a2[c][n4 * 4 + 1] = t4.y;
            a2[c][n4 * 4 + 2] = t4.z; a2[c][n4 * 4 + 3] = t4.w;
        }
    }
    float4 dvv = *(const float4*)(Dv + ch0);
    float dv[4] = {dvv.x, dvv.y, dvv.z, dvv.w};
#pragma unroll
    for (int t = 0; t < 3; ++t)
        if (s0 - 3 + t < 0) uw[t] = make_ushort4(0, 0, 0, 0);
    __syncthreads();

#pragma unroll
    for (int j = 0; j < 8; ++j) {
        float delta = sdg[j * 17];
        float Gr[16];
#pragma unroll
        for (int n = 0; n < 16; ++n) Gr[n] = sdg[j * 17 + 1 + n];
        unsigned short ov[4];
#pragma unroll
        for (int c = 0; c < 4; ++c) {
            float acc = 0.f;
#pragma unroll
            for (int k = 0; k < 4; ++k)
                acc += b2f(u4get(uw[j + k], c)) * w[c][k];
            float xc = silu_f(acc);
            float ssum = 0.f;
#pragma unroll
            for (int n = 0; n < 16; ++n)
                ssum += Gr[n] * __builtin_amdgcn_exp2f(delta * a2[c][n]);
            float y = xc * (dv[c] + ssum);
            ov[c] = f2b(y * silu_f(b2f(u4get(zu[j], c))));
        }
        *(ushort4*)(y2 + (size_t)(m0 + j) * 2048 + ch0) = make_ushort4(ov[0], ov[1], ov[2], ov[3]);
    }
}

// ---------- launch ----------
extern "C" void kernel_launch(void* const* d_in, const int* in_sizes, int n_in,
                              void* d_out, int out_size, void* d_ws, size_t ws_size,
                              hipStream_t stream) {
    const float* x      = (const float*)d_in[0];   // (2,2048,1024)
    const float* W_in   = (const float*)d_in[1];   // (4096,1024)
    const float* conv_w = (const float*)d_in[2];   // (2048,1,4)
    const float* W_x    = (const float*)d_in[3];   // (33,2048)
    const float* A_log  = (const float*)d_in[4];   // (2048,16)
    const float* Dvec   = (const float*)d_in[5];   // (2048,)
    const float* W_out  = (const float*)d_in[6];   // (1024,2048)

    char* ws = (char*)d_ws;
    unsigned short* xb  = (unsigned short*)(ws);              //  8,388,608  x bf16
    unsigned short* wib = (unsigned short*)(ws + 8388608);    //  8,388,608  W_in bf16
    unsigned short* wob = (unsigned short*)(ws + 16777216);   //  4,194,304  W_out bf16
    unsigned short* xz  = (unsigned short*)(ws + 20971520);   // 33,554,432  xz bf16 (4096x4096)
    unsigned short* y2  = (unsigned short*)(ws + 54525952);   // 16,777,216  y2 bf16 (4096x2048)
    unsigned short* wxb = (unsigned short*)(ws + 71303168);   //    196,608  Wx bf16 (48x2048 padded)
    float*          dgp = (float*)        (ws + 71499776);    //    278,528  delta+G (4096x17)
    float*          a2p = (float*)        (ws + 71778304);    //    131,072  A2 (2048x16)

    cast_xw_k<<<8192, 256, 0, stream>>>(x, W_in, xb, wib);
    // blocks 0..2145 cast W_out/W_x/A2; blocks 2146.. compute xz = xb @ wib^T
    gemm1_cast_k<<<3170, 256, 0, stream>>>(xb, wib, xz, W_out, W_x, A_log, wob, wxb, a2p);
    // A: conv+silu -> xproj -> delta/G
    conv_xproj_k<<<512, 256, 0, stream>>>(xz, conv_w, wxb, dgp);
    // B: conv (per-thread-channel) + SSM + gate -> y2
    conv_ssm_k<<<dim3(2, 512), 256, 0, stream>>>(xz, conv_w, dgp, a2p, Dvec, y2);
    // out[m,h] = sum_i y2[m,i] * W_out[h,i]
    gemm_bt_64<<<dim3(16, 64), 256, 0, stream>>>(y2, wob, (float*)d_out, 1024, 2048);
}